// Round 15
// baseline (1255.223 us; speedup 1.0000x reference)
//
#include <hip/hip_runtime.h>
#include <math.h>
#include <stdint.h>

#define BATCH 4096
#define MCAND 50
#define NTOP 32
#define HID 100
#define TFL 20200                  /* floats per (T1,T2) table: 101*100*2 */
#define EPS_ROWS 98
#define EPS_ROWSZ (BATCH*MCAND)              /* 204800 */
#define WS_NEED   (1024u + (size_t)EPS_ROWS*EPS_ROWSZ*4u)

#define MINVC  (-0x1.fffffep-1f)   /* nextafter(-1,0) */
#define SQRT2C (0x1.6a09e6p+0f)    /* fp32 sqrt(2) */

__device__ __forceinline__ uint32_t rotl32(uint32_t v, int d){ return (v<<d)|(v>>(32-d)); }

// JAX threefry2x32 core (20 rounds, 5 key injections)
__device__ __forceinline__ void tf2x32(uint32_t k0, uint32_t k1, uint32_t x0, uint32_t x1,
                                       uint32_t &o0, uint32_t &o1){
  uint32_t k2 = k0 ^ k1 ^ 0x1BD11BDAu;
  x0 += k0; x1 += k1;
#define RND(r) { x0 += x1; x1 = rotl32(x1,(r)); x1 ^= x0; }
  RND(13) RND(15) RND(26) RND(6)
  x0 += k1; x1 += k2 + 1u;
  RND(17) RND(29) RND(16) RND(24)
  x0 += k2; x1 += k0 + 2u;
  RND(13) RND(15) RND(26) RND(6)
  x0 += k0; x1 += k1 + 3u;
  RND(17) RND(29) RND(16) RND(24)
  x0 += k1; x1 += k2 + 4u;
  RND(13) RND(15) RND(26) RND(6)
  x0 += k2; x1 += k0 + 5u;
#undef RND
  o0 = x0; o1 = x1;
}

// XLA ErfInv32 (Giles). w = -log1p(-x*x)
__device__ __forceinline__ float erfinv32(float x){
  float w = -log1pf(-x*x);
  float p;
  if (w < 5.0f){
    w = w - 2.5f;
    p = 2.81022636e-08f;
    p = fmaf(p, w, 3.43273939e-07f);
    p = fmaf(p, w, -3.5233877e-06f);
    p = fmaf(p, w, -4.39150654e-06f);
    p = fmaf(p, w, 0.00021858087f);
    p = fmaf(p, w, -0.00125372503f);
    p = fmaf(p, w, -0.00417768164f);
    p = fmaf(p, w, 0.246640727f);
    p = fmaf(p, w, 1.50140941f);
  } else {
    w = sqrtf(w) - 3.0f;
    p = -0.000200214257f;
    p = fmaf(p, w, 0.000100950558f);
    p = fmaf(p, w, 0.00134934322f);
    p = fmaf(p, w, -0.00367342844f);
    p = fmaf(p, w, 0.00573950773f);
    p = fmaf(p, w, -0.0076224613f);
    p = fmaf(p, w, 0.00943887047f);
    p = fmaf(p, w, 1.00167406f);
    p = fmaf(p, w, 2.83297682f);
  }
  return p*x;
}

// ---- VALU-only lane exchanges (no DS pipe) ----
#define DPPF(v, CTRL) __int_as_float(__builtin_amdgcn_update_dpp( \
    0, __float_as_int(v), (CTRL), 0xF, 0xF, true))
#define DPPI(v, CTRL) __builtin_amdgcn_update_dpp(0, (v), (CTRL), 0xF, 0xF, true)
#define DPPADD(v, CTRL) ((v) + DPPF((v), (CTRL)))

__device__ __forceinline__ float fswap4(float v){        // v[lane^4]
  float a = DPPF(v, 0x114);   // row_shr:4
  float b = DPPF(v, 0x104);   // row_shl:4
  return (threadIdx.x & 4) ? a : b;
}
__device__ __forceinline__ int iswap4(int v){
  int a = DPPI(v, 0x114), b = DPPI(v, 0x104);
  return (threadIdx.x & 4) ? a : b;
}
__device__ __forceinline__ float fswap8(float v){        // v[lane^8] = row_ror:8
  return DPPF(v, 0x128);
}
__device__ __forceinline__ float fswap16(float v){       // v[lane^16]
#if __has_builtin(__builtin_amdgcn_permlane16_swap)
  auto r = __builtin_amdgcn_permlane16_swap(__float_as_uint(v), __float_as_uint(v), false, false);
  return __uint_as_float((threadIdx.x & 16) ? r[0] : r[1]);
#else
  return __shfl_xor(v, 16, 64);
#endif
}
__device__ __forceinline__ float fswap32(float v){       // v[lane^32]
#if __has_builtin(__builtin_amdgcn_permlane32_swap)
  auto r = __builtin_amdgcn_permlane32_swap(__float_as_uint(v), __float_as_uint(v), false, false);
  return __uint_as_float((threadIdx.x & 32) ? r[0] : r[1]);
#else
  return __shfl_xor(v, 32, 64);
#endif
}

// LDS-only barrier: s_waitcnt lgkmcnt(0) + s_barrier, WITHOUT the vmcnt(0)
// drain __syncthreads() emits. In-flight global loads (register-private eps)
// cross the barrier; the compiler inserts the vmcnt wait at first USE.
__device__ __forceinline__ void bar_lgkm(){
  asm volatile("s_waitcnt lgkmcnt(0)\n\ts_barrier" ::: "memory");
}

// ---------------------------------------------------------------------------
// Pre-kernels (r8): one thread produces TWO eps values (threefry r0 -> g,
// r1 -> g+102400). Layout [t][g]; in-loop row load is 50 contiguous floats.
// ---------------------------------------------------------------------------
__global__ void keys_kernel(uint32_t* __restrict__ K){
  int tid = threadIdx.x;
  if (tid < 99){
    uint32_t A0, B0, A1, B1;
    tf2x32(0u,42u,0u,2u,A0,A1);
    tf2x32(0u,42u,1u,3u,B0,B1);
    (void)A0; (void)B0;
    uint32_t o0,o1;
    tf2x32(A1,B1,(uint32_t)tid,(uint32_t)(99+tid),o0,o1);
    K[tid]    = o0;
    K[99+tid] = o1;
  }
}

__device__ __forceinline__ float bits2norm(uint32_t bits){
  float fl = __uint_as_float((bits>>9) | 0x3f800000u) - 1.0f;
  float u  = fmaxf(MINVC, fl*2.0f + MINVC);
  return SQRT2C * erfinv32(u);
}

__global__ __launch_bounds__(256) void eps_kernel(const uint32_t* __restrict__ K,
                                                  float* __restrict__ E){
  int id = blockIdx.x*256 + threadIdx.x;     // 98 * 102400 threads
  int t  = id / 102400;
  int g  = id - t*102400;
  uint32_t kk0 = K[2*t], kk1 = K[2*t+1];
  uint32_t r0, r1;
  tf2x32(kk0,kk1,(uint32_t)g,(uint32_t)g+102400u,r0,r1);
  E[(size_t)t*EPS_ROWSZ + g]           = bits2norm(r0);
  E[(size_t)t*EPS_ROWSZ + g + 102400]  = bits2norm(r1);
}

// ---------------------------------------------------------------------------
// Piecewise-linear CEM — r11 (session best, reproduced at 1140us main) plus
// ONE isolated change: STATS-WAVE SIMD SPLIT.
//   stats wave (and its loop-top eps issue) = wave((b>>8)&1).
// Co-resident partners {b, b+256} then run their serial bitonic chains on
// SIMD0 vs SIMD1 -> concurrent instead of time-slicing SIMD0 when the
// blocks drift in-phase. Same bit drives the r10 anti-phase sleep, so
// partners differ in both phase and stats-SIMD. Replicated stats code is
// deterministic -> bit-identical output regardless of executing wave.
// (r13 bundled this with an S-tail prefetch restructure that moved the eps
// vmcnt wait inside the stats chain — that part is NOT repeated here.)
// LDS: table 20,200 + AQ 50 + EPB 50 = 81,200 B -> 2 blocks/CU.
// ---------------------------------------------------------------------------
template<bool EPSG>
__global__ __launch_bounds__(512) void cem_kernel(
    const float* __restrict__ states, const float* __restrict__ W1,
    const float* __restrict__ b1,     const float* __restrict__ W2,
    const float* __restrict__ b2,     const float* __restrict__ W3,
    const float* __restrict__ b3,     const float* __restrict__ epsg,
    float* __restrict__ out)
{
  __shared__ __align__(16) float smem[20300];           // 81,200 B
  float*  const Tb   = smem;                            // table region
  float2* const T2D  = (float2*)Tb;                     // [101][100] (T1,T2)
  int*    const ORD  = (int*)(Tb + 300);                // init scratch (in T)
  float*  const STm  = Tb + 400;                        // init scratch (in T)
  float*  const AQ   = smem + 20200;                    // [50] angles <-> q
  float*  const EPB  = smem + 20250;                    // [50] eps (fallback)

  const int tid  = threadIdx.x;
  const int b    = blockIdx.x;
  const int wv   = tid >> 6;
  const int lane = tid & 63;
  const int gc   = tid >> 3;            // gather candidate (8 lanes/cand)
  const int gj   = tid & 7;
  const bool gact = (tid < 8*MCAND);    // tid < 400 (waves 0-6)
  const int SW   = (b >> 8) & 1;        // stats wave: 0 or 1 (SIMD0/SIMD1)

  // per-thread W3 slice for the gather (n = gj + 8i)
  float w3r[13];
#pragma unroll
  for (int i = 0; i < 13; ++i){
    int n = gj + (i<<3);
    w3r[i] = (n < HID) ? W3[n] : 0.0f;
  }
  const float sB3v = b3[0];

  // fallback-path wave7 register state
  uint32_t A1k = 0u, B1k = 0u, kk0 = 0u, kk1 = 0u;

  // ---------- init P0: u,v,thresholds; angles0; (fallback) key state ----------
  if (tid < HID){
    float u = fmaf(states[2*b], W1[tid], fmaf(states[2*b+1], W1[HID+tid], b1[tid]));
    float v = W1[2*HID+tid];
    float tt = (v != 0.0f) ? (-u / v) : INFINITY;
    Tb[tid]     = u;
    Tb[HID+tid] = v;
    Tb[200+tid] = tt;
  }
  if (tid >= 128 && tid < 128 + MCAND){
    // iteration-0 uniform angles (mu=0, std=1)
    int c = tid - 128;
    uint32_t A0, B0, a1t, b1t;
    tf2x32(0u,42u,0u,2u,A0,a1t);
    tf2x32(0u,42u,1u,3u,B0,b1t);
    uint32_t gidx = (uint32_t)b*MCAND + (uint32_t)c;
    uint32_t r0,r1,bits;
    if (gidx < 102400u){ tf2x32(A0,B0,gidx,gidx+102400u,r0,r1); bits = r0; }
    else               { tf2x32(A0,B0,gidx-102400u,gidx,r0,r1); bits = r1; }
    AQ[c] = __uint_as_float((bits>>9) | 0x3f800000u) - 1.0f;
  }
  if (!EPSG && wv == 7){
    uint32_t A0, B0;
    tf2x32(0u,42u,0u,2u,A0,A1k);
    tf2x32(0u,42u,1u,3u,B0,B1k);
    { uint32_t i0 = 0u; uint32_t x,y; tf2x32(A1k,B1k, i0, 99u+i0, x, y); kk0 = x; }
    { uint32_t i1 = 1u; uint32_t x,y; tf2x32(A1k,B1k, i1, 99u+i1, x, y); kk1 = x; }
  }
  __syncthreads();

  // ---------- init P1: stable rank-by-count, scatter sorted ----------
  if (tid < HID){
    float tk = Tb[200+tid];
    int rk = 0;
    for (int j2 = 0; j2 < HID; ++j2){
      float tj = Tb[200+j2];
      rk += (tj < tk || (tj == tk && j2 < tid)) ? 1 : 0;
    }
    float u = Tb[tid], v = Tb[HID+tid];
    // neg-type: active iff a < t (v<0, or v==0 with u>0 -> always active, t=+inf)
    int neg = (v < 0.0f || (v == 0.0f && u > 0.0f)) ? 1 : 0;
    STm[rk] = tk;
    ORD[rk] = tid | (neg << 7);
  }
  __syncthreads();

  // ---------- init P1.5: builder meta -> regs (wave0); thresholds -> regs ----------
  int kpA = 0, kpB = 0; float cuA = 0.f, cvA = 0.f, cuB = 0.f, cvB = 0.f;
  if (wv == 0){
    kpA = ORD[lane];
    int kiA = kpA & 127;
    float uA = Tb[kiA], vA = Tb[HID+kiA];
    cuA = (kpA & 128) ? -uA : uA;     // signed delta for prefix pass
    cvA = (kpA & 128) ? -vA : vA;
    if (lane < 36){
      kpB = ORD[64+lane];
      int kiB = kpB & 127;
      float uB = Tb[kiB], vB = Tb[HID+kiB];
      cuB = (kpB & 128) ? -uB : uB;
      cvB = (kpB & 128) ? -vB : vB;
    }
  }
  float st_r[13];                       // loop-invariant thresholds in regs
#pragma unroll
  for (int i = 0; i < 13; ++i){
    int idx = gj*13 + i;
    st_r[i] = (idx < HID) ? STm[idx] : INFINITY;
  }
  __syncthreads();   // meta/thresholds consumed; T scratch region now dead

  // ---------- init P2: wave0 builds the 101-row prefix table ----------
  if (wv == 0){
    const int L = lane;          // columns n=L and n=64+L (L<36)
    float a10 = b2[L], a20 = 0.0f;
    float a11 = (L < 36) ? b2[64+L] : 0.0f, a21 = 0.0f;
    // pass 1: rank-0 base = b2 + sum over neg-type features of (+u,+v)*W2row
#pragma unroll 8
    for (int rr = 0; rr < 64; ++rr){
      int   kp = __builtin_amdgcn_readlane(kpA, rr);
      float cu = __int_as_float(__builtin_amdgcn_readlane(__float_as_int(cuA), rr));
      float cv = __int_as_float(__builtin_amdgcn_readlane(__float_as_int(cvA), rr));
      int k = kp & 127;
      float bu = (kp & 128) ? -cu : 0.0f;  // = +u for neg-type, 0 for pos-type
      float bv = (kp & 128) ? -cv : 0.0f;
      float w0 = W2[k*HID + L];
      a10 = fmaf(bu, w0, a10); a20 = fmaf(bv, w0, a20);
      if (L < 36){
        float w1 = W2[k*HID + 64+L];
        a11 = fmaf(bu, w1, a11); a21 = fmaf(bv, w1, a21);
      }
    }
#pragma unroll 6
    for (int rr = 0; rr < 36; ++rr){
      int   kp = __builtin_amdgcn_readlane(kpB, rr);
      float cu = __int_as_float(__builtin_amdgcn_readlane(__float_as_int(cuB), rr));
      float cv = __int_as_float(__builtin_amdgcn_readlane(__float_as_int(cvB), rr));
      int k = kp & 127;
      float bu = (kp & 128) ? -cu : 0.0f;
      float bv = (kp & 128) ? -cv : 0.0f;
      float w0 = W2[k*HID + L];
      a10 = fmaf(bu, w0, a10); a20 = fmaf(bv, w0, a20);
      if (L < 36){
        float w1 = W2[k*HID + 64+L];
        a11 = fmaf(bu, w1, a11); a21 = fmaf(bv, w1, a21);
      }
    }
    { float2 f; f.x = a10; f.y = a20; T2D[L] = f; }
    if (L < 36){ float2 f; f.x = a11; f.y = a21; T2D[64+L] = f; }
    // pass 2: ascending ranks, signed deltas, write T[rr+1]
#pragma unroll 8
    for (int rr = 0; rr < 64; ++rr){
      int   kp = __builtin_amdgcn_readlane(kpA, rr);
      float cu = __int_as_float(__builtin_amdgcn_readlane(__float_as_int(cuA), rr));
      float cv = __int_as_float(__builtin_amdgcn_readlane(__float_as_int(cvA), rr));
      int k = kp & 127;
      float w0 = W2[k*HID + L];
      a10 = fmaf(cu, w0, a10); a20 = fmaf(cv, w0, a20);
      { float2 f; f.x = a10; f.y = a20; T2D[(rr+1)*HID + L] = f; }
      if (L < 36){
        float w1 = W2[k*HID + 64+L];
        a11 = fmaf(cu, w1, a11); a21 = fmaf(cv, w1, a21);
        float2 f; f.x = a11; f.y = a21; T2D[(rr+1)*HID + 64+L] = f;
      }
    }
#pragma unroll 6
    for (int rr = 0; rr < 36; ++rr){
      int   kp = __builtin_amdgcn_readlane(kpB, rr);
      float cu = __int_as_float(__builtin_amdgcn_readlane(__float_as_int(cuB), rr));
      float cv = __int_as_float(__builtin_amdgcn_readlane(__float_as_int(cvB), rr));
      int k = kp & 127;
      float w0 = W2[k*HID + L];
      a10 = fmaf(cu, w0, a10); a20 = fmaf(cv, w0, a20);
      { float2 f; f.x = a10; f.y = a20; T2D[(65+rr)*HID + L] = f; }
      if (L < 36){
        float w1 = W2[k*HID + 64+L];
        a11 = fmaf(cu, w1, a11); a21 = fmaf(cv, w1, a21);
        float2 f; f.x = a11; f.y = a21; T2D[(65+rr)*HID + 64+L] = f;
      }
    }
  }
  __syncthreads();   // table + angles0 visible (full drain: init has VMEM)

  // ---------- ANTI-PHASE: offset the second co-resident stream ~960 cyc ----------
  if ((b >> 8) & 1) __builtin_amdgcn_s_sleep(15);

  // ---------- CEM loop: 99 evaluations ----------
#pragma unroll 1
  for (int t = 0; t < 99; ++t){
    // --- stats wave: issue eps row t load FIRST (consumed in S after B1;
    //     the lgkm-only barrier lets it stay in flight -> latency hidden) ---
    float epsv = 0.0f;
    if (EPSG && wv == SW && lane < MCAND && t < EPS_ROWS)
      epsv = epsg[(size_t)t*EPS_ROWSZ + (size_t)b*MCAND + (size_t)lane];

    // --- G: q_c = sum_n relu(T1[r][n] + a*T2[r][n]) * W3[n] ---
    if (gact){
      const float av = AQ[gc];            // LDS broadcast (8 lanes same addr)
      int rk = 0;
#pragma unroll
      for (int i = 0; i < 13; ++i) rk += (st_r[i] < av) ? 1 : 0;
      rk += DPPI(rk, 0xB1);
      rk += DPPI(rk, 0x4E);
      rk += iswap4(rk);
      // stride-uniform addressing: byte base once, imm-offset b64 reads
      const char* rowp = (const char*)T2D + (((rk*HID) + gj) << 3);
      float acc = 0.0f;
#pragma unroll
      for (int i = 0; i < 12; ++i){
        float2 tv = *(const float2*)(rowp + (i << 6));   // n = gj + 8i
        float h = fmaxf(fmaf(av, tv.y, tv.x), 0.0f);
        acc = fmaf(h, w3r[i], acc);
      }
      if (gj < 4){                        // tail n = 96+gj (others added +0)
        float2 tv = *(const float2*)(rowp + (12 << 6));
        float h = fmaxf(fmaf(av, tv.y, tv.x), 0.0f);
        acc = fmaf(h, w3r[12], acc);
      }
      acc = DPPADD(acc, 0xB1);
      acc = DPPADD(acc, 0x4E);
      acc += fswap4(acc);
      if (gj == 0) AQ[gc] = acc;          // q overwrites a (own group's slot)
    }
    // --- fallback: per-iter eps on wave 7 (VALU only, LDS write) ---
    if (!EPSG && wv == 7 && t < EPS_ROWS && lane < MCAND){
      uint32_t gidx = (uint32_t)b*MCAND + (uint32_t)lane;
      uint32_t r0, r1, bits;
      if (gidx < 102400u){ tf2x32(kk0,kk1,gidx,gidx+102400u,r0,r1); bits = r0; }
      else               { tf2x32(kk0,kk1,gidx-102400u,gidx,r0,r1); bits = r1; }
      EPB[lane] = bits2norm(bits);
    }
    bar_lgkm();        // B1: q(t) (+fallback eps) visible; eps load in flight

    // --- S: stats wave SW (prio-boosted); (fallback) wave7 computes kk(t+1) ---
    if (wv == SW){
      __builtin_amdgcn_s_setprio(1);
      float q = (lane < MCAND) ? (AQ[lane] + sB3v) : -INFINITY;
      // sort 32-halves in opposite directions, j=32 max-merge -> top-32 multiset
      float v = q;
#define BST(KK, JJ, PV) { float pv = (PV); bool lower = (lane & (JJ)) == 0; \
        bool asc = (lane & (KK)) != 0; float mn = fminf(v, pv), mx = fmaxf(v, pv); \
        v = (lower == asc) ? mn : mx; }
      BST(2, 1,  DPPF(v, 0xB1))
      BST(4, 2,  DPPF(v, 0x4E))
      BST(4, 1,  DPPF(v, 0xB1))
      BST(8, 4,  fswap4(v))
      BST(8, 2,  DPPF(v, 0x4E))
      BST(8, 1,  DPPF(v, 0xB1))
      BST(16, 8, fswap8(v))
      BST(16, 4, fswap4(v))
      BST(16, 2, DPPF(v, 0x4E))
      BST(16, 1, DPPF(v, 0xB1))
      BST(32, 16, fswap16(v))
      BST(32, 8,  fswap8(v))
      BST(32, 4,  fswap4(v))
      BST(32, 2,  DPPF(v, 0x4E))
      BST(32, 1,  DPPF(v, 0xB1))
#undef BST
      {
        float pv = fswap32(v);
        v = ((lane & 32) == 0) ? fmaxf(v, pv) : fminf(v, pv);
      }
      // sum / sum-of-squares over lanes 0..31 (same add order as r2..r11)
      float sv = (lane < NTOP) ? v : 0.0f;
      sv += fswap32(sv);
      sv += fswap16(sv);
      sv += fswap8(sv);
      sv += fswap4(sv);
      sv = DPPADD(sv, 0x4E);
      sv = DPPADD(sv, 0xB1);
      float mun = sv / 32.0f;
      float dv = (lane < NTOP) ? (v - mun) : 0.0f;
      float s2 = dv*dv;
      s2 += fswap32(s2);
      s2 += fswap16(s2);
      s2 += fswap8(s2);
      s2 += fswap4(s2);
      s2 = DPPADD(s2, 0x4E);
      s2 = DPPADD(s2, 0xB1);
      float stdv = sqrtf(s2 / 31.0f);
      if (t == 98){
        if (lane == 0) out[b] = mun * 6.2831854820251465f;  // fp32(2*pi)
      } else if (lane < MCAND){
        float e = EPSG ? epsv : EPB[lane];   // vmcnt wait lands HERE (hidden)
        AQ[lane] = fmaf(stdv, e, mun);       // a(t+1)
      }
      __builtin_amdgcn_s_setprio(0);
    } else if (!EPSG && wv == 7 && t < EPS_ROWS){
      uint32_t nt = (uint32_t)(t + 1);
      { uint32_t i0 = 2u*nt;      uint32_t ii = (i0 < 99u) ? i0 : (i0 - 99u);
        uint32_t x,y; tf2x32(A1k,B1k, ii, 99u+ii, x, y); kk0 = (i0 < 99u) ? x : y; }
      { uint32_t i1 = 2u*nt + 1u; uint32_t ii = (i1 < 99u) ? i1 : (i1 - 99u);
        uint32_t x,y; tf2x32(A1k,B1k, ii, 99u+ii, x, y); kk1 = (i1 < 99u) ? x : y; }
    }
    bar_lgkm();        // B2: a(t+1) visible
  }
}

extern "C" void kernel_launch(void* const* d_in, const int* in_sizes, int n_in,
                              void* d_out, int out_size, void* d_ws, size_t ws_size,
                              hipStream_t stream) {
  const float* states = (const float*)d_in[0];
  const float* W1     = (const float*)d_in[1];
  const float* b1     = (const float*)d_in[2];
  const float* W2     = (const float*)d_in[3];
  const float* b2     = (const float*)d_in[4];
  const float* W3     = (const float*)d_in[5];
  const float* b3     = (const float*)d_in[6];
  float* out = (float*)d_out;

  if (d_ws != nullptr && ws_size >= WS_NEED){
    uint32_t* K = (uint32_t*)d_ws;
    float*    E = (float*)((char*)d_ws + 1024);
    hipLaunchKernelGGL(keys_kernel, dim3(1), dim3(128), 0, stream, K);
    hipLaunchKernelGGL(eps_kernel, dim3(EPS_ROWS*102400/256), dim3(256), 0, stream, K, E);
    hipLaunchKernelGGL(HIP_KERNEL_NAME(cem_kernel<true>), dim3(BATCH), dim3(512), 0, stream,
                       states, W1, b1, W2, b2, W3, b3, (const float*)E, out);
  } else {
    hipLaunchKernelGGL(HIP_KERNEL_NAME(cem_kernel<false>), dim3(BATCH), dim3(512), 0, stream,
                       states, W1, b1, W2, b2, W3, b3, (const float*)nullptr, out);
  }
}

// Round 17
// 1232.474 us; speedup vs baseline: 1.0185x; 1.0185x over previous
//
#include <hip/hip_runtime.h>
#include <math.h>
#include <stdint.h>

#define BATCH 4096
#define MCAND 50
#define NTOP 32
#define HID 100
#define TFL 20200                  /* floats per (T1,T2) table: 101*100*2 */
#define EPS_ROWS 98
#define EPS_ROWSZ (BATCH*MCAND)              /* 204800 */
#define WS_NEED   (1024u + (size_t)EPS_ROWS*EPS_ROWSZ*4u)

#define MINVC  (-0x1.fffffep-1f)   /* nextafter(-1,0) */
#define SQRT2C (0x1.6a09e6p+0f)    /* fp32 sqrt(2) */

__device__ __forceinline__ uint32_t rotl32(uint32_t v, int d){ return (v<<d)|(v>>(32-d)); }

// JAX threefry2x32 core (20 rounds, 5 key injections)
__device__ __forceinline__ void tf2x32(uint32_t k0, uint32_t k1, uint32_t x0, uint32_t x1,
                                       uint32_t &o0, uint32_t &o1){
  uint32_t k2 = k0 ^ k1 ^ 0x1BD11BDAu;
  x0 += k0; x1 += k1;
#define RND(r) { x0 += x1; x1 = rotl32(x1,(r)); x1 ^= x0; }
  RND(13) RND(15) RND(26) RND(6)
  x0 += k1; x1 += k2 + 1u;
  RND(17) RND(29) RND(16) RND(24)
  x0 += k2; x1 += k0 + 2u;
  RND(13) RND(15) RND(26) RND(6)
  x0 += k0; x1 += k1 + 3u;
  RND(17) RND(29) RND(16) RND(24)
  x0 += k1; x1 += k2 + 4u;
  RND(13) RND(15) RND(26) RND(6)
  x0 += k2; x1 += k0 + 5u;
#undef RND
  o0 = x0; o1 = x1;
}

// XLA ErfInv32 (Giles). w = -log1p(-x*x)
__device__ __forceinline__ float erfinv32(float x){
  float w = -log1pf(-x*x);
  float p;
  if (w < 5.0f){
    w = w - 2.5f;
    p = 2.81022636e-08f;
    p = fmaf(p, w, 3.43273939e-07f);
    p = fmaf(p, w, -3.5233877e-06f);
    p = fmaf(p, w, -4.39150654e-06f);
    p = fmaf(p, w, 0.00021858087f);
    p = fmaf(p, w, -0.00125372503f);
    p = fmaf(p, w, -0.00417768164f);
    p = fmaf(p, w, 0.246640727f);
    p = fmaf(p, w, 1.50140941f);
  } else {
    w = sqrtf(w) - 3.0f;
    p = -0.000200214257f;
    p = fmaf(p, w, 0.000100950558f);
    p = fmaf(p, w, 0.00134934322f);
    p = fmaf(p, w, -0.00367342844f);
    p = fmaf(p, w, 0.00573950773f);
    p = fmaf(p, w, -0.0076224613f);
    p = fmaf(p, w, 0.00943887047f);
    p = fmaf(p, w, 1.00167406f);
    p = fmaf(p, w, 2.83297682f);
  }
  return p*x;
}

// ---- VALU-only lane exchanges (no DS pipe) ----
#define DPPF(v, CTRL) __int_as_float(__builtin_amdgcn_update_dpp( \
    0, __float_as_int(v), (CTRL), 0xF, 0xF, true))
#define DPPI(v, CTRL) __builtin_amdgcn_update_dpp(0, (v), (CTRL), 0xF, 0xF, true)
#define DPPADD(v, CTRL) ((v) + DPPF((v), (CTRL)))

__device__ __forceinline__ float fswap4(float v){        // v[lane^4]
  float a = DPPF(v, 0x114);   // row_shr:4
  float b = DPPF(v, 0x104);   // row_shl:4
  return (threadIdx.x & 4) ? a : b;
}
__device__ __forceinline__ int iswap4(int v){
  int a = DPPI(v, 0x114), b = DPPI(v, 0x104);
  return (threadIdx.x & 4) ? a : b;
}
__device__ __forceinline__ float fswap8(float v){        // v[lane^8] = row_ror:8
  return DPPF(v, 0x128);
}
__device__ __forceinline__ float fswap16(float v){       // v[lane^16]
#if __has_builtin(__builtin_amdgcn_permlane16_swap)
  auto r = __builtin_amdgcn_permlane16_swap(__float_as_uint(v), __float_as_uint(v), false, false);
  return __uint_as_float((threadIdx.x & 16) ? r[0] : r[1]);
#else
  return __shfl_xor(v, 16, 64);
#endif
}
__device__ __forceinline__ float fswap32(float v){       // v[lane^32]
#if __has_builtin(__builtin_amdgcn_permlane32_swap)
  auto r = __builtin_amdgcn_permlane32_swap(__float_as_uint(v), __float_as_uint(v), false, false);
  return __uint_as_float((threadIdx.x & 32) ? r[0] : r[1]);
#else
  return __shfl_xor(v, 32, 64);
#endif
}

// LDS-only barrier: s_waitcnt lgkmcnt(0) + s_barrier, WITHOUT the vmcnt(0)
// drain __syncthreads() emits. In-flight global loads (register-private eps)
// cross the barrier; the compiler inserts the vmcnt wait at first USE.
__device__ __forceinline__ void bar_lgkm(){
  asm volatile("s_waitcnt lgkmcnt(0)\n\ts_barrier" ::: "memory");
}

// ---------------------------------------------------------------------------
// Pre-kernels (r8): one thread produces TWO eps values (threefry r0 -> g,
// r1 -> g+102400). Layout [t][g]; in-loop row load is 50 contiguous floats.
// ---------------------------------------------------------------------------
__global__ void keys_kernel(uint32_t* __restrict__ K){
  int tid = threadIdx.x;
  if (tid < 99){
    uint32_t A0, B0, A1, B1;
    tf2x32(0u,42u,0u,2u,A0,A1);
    tf2x32(0u,42u,1u,3u,B0,B1);
    (void)A0; (void)B0;
    uint32_t o0,o1;
    tf2x32(A1,B1,(uint32_t)tid,(uint32_t)(99+tid),o0,o1);
    K[tid]    = o0;
    K[99+tid] = o1;
  }
}

__device__ __forceinline__ float bits2norm(uint32_t bits){
  float fl = __uint_as_float((bits>>9) | 0x3f800000u) - 1.0f;
  float u  = fmaxf(MINVC, fl*2.0f + MINVC);
  return SQRT2C * erfinv32(u);
}

__global__ __launch_bounds__(256) void eps_kernel(const uint32_t* __restrict__ K,
                                                  float* __restrict__ E){
  int id = blockIdx.x*256 + threadIdx.x;     // 98 * 102400 threads
  int t  = id / 102400;
  int g  = id - t*102400;
  uint32_t kk0 = K[2*t], kk1 = K[2*t+1];
  uint32_t r0, r1;
  tf2x32(kk0,kk1,(uint32_t)g,(uint32_t)g+102400u,r0,r1);
  E[(size_t)t*EPS_ROWSZ + g]           = bits2norm(r0);
  E[(size_t)t*EPS_ROWSZ + g + 102400]  = bits2norm(r1);
}

// ---------------------------------------------------------------------------
// Piecewise-linear CEM — FINAL: exact r11 (session best, 1234us total /
// 1140us main, reproduced three times; r16 resubmission after an infra-level
// container failure with no evidence the kernel ran).
//
// Structure: prefix tables (exact fp32 piecewise-linear NN collapse:
// h2pre[n] = T1[r][n] + a*T2[r][n], r = #{t_k < a});
// loop = G(waves0-6 gather, wave0 issues eps row load at loop top) ->
// bar_lgkm (no vmcnt drain; load stays in flight) -> S(wave0 bitonic
// top-32 stats, setprio(1); eps vmcnt wait lands at consume) -> bar_lgkm.
// Anti-phase sleep on half the blocks (r10: +6%).
// LDS: table 20,200 + AQ 50 + EPB 50 = 81,200 B -> 2 blocks/CU.
// ---------------------------------------------------------------------------
template<bool EPSG>
__global__ __launch_bounds__(512) void cem_kernel(
    const float* __restrict__ states, const float* __restrict__ W1,
    const float* __restrict__ b1,     const float* __restrict__ W2,
    const float* __restrict__ b2,     const float* __restrict__ W3,
    const float* __restrict__ b3,     const float* __restrict__ epsg,
    float* __restrict__ out)
{
  __shared__ __align__(16) float smem[20300];           // 81,200 B
  float*  const Tb   = smem;                            // table region
  float2* const T2D  = (float2*)Tb;                     // [101][100] (T1,T2)
  int*    const ORD  = (int*)(Tb + 300);                // init scratch (in T)
  float*  const STm  = Tb + 400;                        // init scratch (in T)
  float*  const AQ   = smem + 20200;                    // [50] angles <-> q
  float*  const EPB  = smem + 20250;                    // [50] eps (fallback)

  const int tid  = threadIdx.x;
  const int b    = blockIdx.x;
  const int wv   = tid >> 6;
  const int lane = tid & 63;
  const int gc   = tid >> 3;            // gather candidate (8 lanes/cand)
  const int gj   = tid & 7;
  const bool gact = (tid < 8*MCAND);    // tid < 400 (waves 0-6)

  // per-thread W3 slice for the gather (n = gj + 8i)
  float w3r[13];
#pragma unroll
  for (int i = 0; i < 13; ++i){
    int n = gj + (i<<3);
    w3r[i] = (n < HID) ? W3[n] : 0.0f;
  }
  const float sB3v = b3[0];

  // fallback-path wave7 register state
  uint32_t A1k = 0u, B1k = 0u, kk0 = 0u, kk1 = 0u;

  // ---------- init P0: u,v,thresholds; angles0; (fallback) key state ----------
  if (tid < HID){
    float u = fmaf(states[2*b], W1[tid], fmaf(states[2*b+1], W1[HID+tid], b1[tid]));
    float v = W1[2*HID+tid];
    float tt = (v != 0.0f) ? (-u / v) : INFINITY;
    Tb[tid]     = u;
    Tb[HID+tid] = v;
    Tb[200+tid] = tt;
  }
  if (tid >= 128 && tid < 128 + MCAND){
    // iteration-0 uniform angles (mu=0, std=1)
    int c = tid - 128;
    uint32_t A0, B0, a1t, b1t;
    tf2x32(0u,42u,0u,2u,A0,a1t);
    tf2x32(0u,42u,1u,3u,B0,b1t);
    uint32_t gidx = (uint32_t)b*MCAND + (uint32_t)c;
    uint32_t r0,r1,bits;
    if (gidx < 102400u){ tf2x32(A0,B0,gidx,gidx+102400u,r0,r1); bits = r0; }
    else               { tf2x32(A0,B0,gidx-102400u,gidx,r0,r1); bits = r1; }
    AQ[c] = __uint_as_float((bits>>9) | 0x3f800000u) - 1.0f;
  }
  if (!EPSG && wv == 7){
    uint32_t A0, B0;
    tf2x32(0u,42u,0u,2u,A0,A1k);
    tf2x32(0u,42u,1u,3u,B0,B1k);
    { uint32_t i0 = 0u; uint32_t x,y; tf2x32(A1k,B1k, i0, 99u+i0, x, y); kk0 = x; }
    { uint32_t i1 = 1u; uint32_t x,y; tf2x32(A1k,B1k, i1, 99u+i1, x, y); kk1 = x; }
  }
  __syncthreads();

  // ---------- init P1: stable rank-by-count, scatter sorted ----------
  if (tid < HID){
    float tk = Tb[200+tid];
    int rk = 0;
    for (int j2 = 0; j2 < HID; ++j2){
      float tj = Tb[200+j2];
      rk += (tj < tk || (tj == tk && j2 < tid)) ? 1 : 0;
    }
    float u = Tb[tid], v = Tb[HID+tid];
    // neg-type: active iff a < t (v<0, or v==0 with u>0 -> always active, t=+inf)
    int neg = (v < 0.0f || (v == 0.0f && u > 0.0f)) ? 1 : 0;
    STm[rk] = tk;
    ORD[rk] = tid | (neg << 7);
  }
  __syncthreads();

  // ---------- init P1.5: builder meta -> regs (wave0); thresholds -> regs ----------
  int kpA = 0, kpB = 0; float cuA = 0.f, cvA = 0.f, cuB = 0.f, cvB = 0.f;
  if (wv == 0){
    kpA = ORD[lane];
    int kiA = kpA & 127;
    float uA = Tb[kiA], vA = Tb[HID+kiA];
    cuA = (kpA & 128) ? -uA : uA;     // signed delta for prefix pass
    cvA = (kpA & 128) ? -vA : vA;
    if (lane < 36){
      kpB = ORD[64+lane];
      int kiB = kpB & 127;
      float uB = Tb[kiB], vB = Tb[HID+kiB];
      cuB = (kpB & 128) ? -uB : uB;
      cvB = (kpB & 128) ? -vB : vB;
    }
  }
  float st_r[13];                       // loop-invariant thresholds in regs
#pragma unroll
  for (int i = 0; i < 13; ++i){
    int idx = gj*13 + i;
    st_r[i] = (idx < HID) ? STm[idx] : INFINITY;
  }
  __syncthreads();   // meta/thresholds consumed; T scratch region now dead

  // ---------- init P2: wave0 builds the 101-row prefix table ----------
  if (wv == 0){
    const int L = lane;          // columns n=L and n=64+L (L<36)
    float a10 = b2[L], a20 = 0.0f;
    float a11 = (L < 36) ? b2[64+L] : 0.0f, a21 = 0.0f;
    // pass 1: rank-0 base = b2 + sum over neg-type features of (+u,+v)*W2row
#pragma unroll 8
    for (int rr = 0; rr < 64; ++rr){
      int   kp = __builtin_amdgcn_readlane(kpA, rr);
      float cu = __int_as_float(__builtin_amdgcn_readlane(__float_as_int(cuA), rr));
      float cv = __int_as_float(__builtin_amdgcn_readlane(__float_as_int(cvA), rr));
      int k = kp & 127;
      float bu = (kp & 128) ? -cu : 0.0f;  // = +u for neg-type, 0 for pos-type
      float bv = (kp & 128) ? -cv : 0.0f;
      float w0 = W2[k*HID + L];
      a10 = fmaf(bu, w0, a10); a20 = fmaf(bv, w0, a20);
      if (L < 36){
        float w1 = W2[k*HID + 64+L];
        a11 = fmaf(bu, w1, a11); a21 = fmaf(bv, w1, a21);
      }
    }
#pragma unroll 6
    for (int rr = 0; rr < 36; ++rr){
      int   kp = __builtin_amdgcn_readlane(kpB, rr);
      float cu = __int_as_float(__builtin_amdgcn_readlane(__float_as_int(cuB), rr));
      float cv = __int_as_float(__builtin_amdgcn_readlane(__float_as_int(cvB), rr));
      int k = kp & 127;
      float bu = (kp & 128) ? -cu : 0.0f;
      float bv = (kp & 128) ? -cv : 0.0f;
      float w0 = W2[k*HID + L];
      a10 = fmaf(bu, w0, a10); a20 = fmaf(bv, w0, a20);
      if (L < 36){
        float w1 = W2[k*HID + 64+L];
        a11 = fmaf(bu, w1, a11); a21 = fmaf(bv, w1, a21);
      }
    }
    { float2 f; f.x = a10; f.y = a20; T2D[L] = f; }
    if (L < 36){ float2 f; f.x = a11; f.y = a21; T2D[64+L] = f; }
    // pass 2: ascending ranks, signed deltas, write T[rr+1]
#pragma unroll 8
    for (int rr = 0; rr < 64; ++rr){
      int   kp = __builtin_amdgcn_readlane(kpA, rr);
      float cu = __int_as_float(__builtin_amdgcn_readlane(__float_as_int(cuA), rr));
      float cv = __int_as_float(__builtin_amdgcn_readlane(__float_as_int(cvA), rr));
      int k = kp & 127;
      float w0 = W2[k*HID + L];
      a10 = fmaf(cu, w0, a10); a20 = fmaf(cv, w0, a20);
      { float2 f; f.x = a10; f.y = a20; T2D[(rr+1)*HID + L] = f; }
      if (L < 36){
        float w1 = W2[k*HID + 64+L];
        a11 = fmaf(cu, w1, a11); a21 = fmaf(cv, w1, a21);
        float2 f; f.x = a11; f.y = a21; T2D[(rr+1)*HID + 64+L] = f;
      }
    }
#pragma unroll 6
    for (int rr = 0; rr < 36; ++rr){
      int   kp = __builtin_amdgcn_readlane(kpB, rr);
      float cu = __int_as_float(__builtin_amdgcn_readlane(__float_as_int(cuB), rr));
      float cv = __int_as_float(__builtin_amdgcn_readlane(__float_as_int(cvB), rr));
      int k = kp & 127;
      float w0 = W2[k*HID + L];
      a10 = fmaf(cu, w0, a10); a20 = fmaf(cv, w0, a20);
      { float2 f; f.x = a10; f.y = a20; T2D[(65+rr)*HID + L] = f; }
      if (L < 36){
        float w1 = W2[k*HID + 64+L];
        a11 = fmaf(cu, w1, a11); a21 = fmaf(cv, w1, a21);
        float2 f; f.x = a11; f.y = a21; T2D[(65+rr)*HID + 64+L] = f;
      }
    }
  }
  __syncthreads();   // table + angles0 visible (full drain: init has VMEM)

  // ---------- ANTI-PHASE: offset the second co-resident stream ~960 cyc ----------
  if ((b >> 8) & 1) __builtin_amdgcn_s_sleep(15);

  // ---------- CEM loop: 99 evaluations ----------
#pragma unroll 1
  for (int t = 0; t < 99; ++t){
    // --- wave0: issue eps row t load FIRST (consumed in S after B1; the
    //     lgkm-only barrier lets it stay in flight -> latency hidden) ---
    float epsv = 0.0f;
    if (EPSG && wv == 0 && lane < MCAND && t < EPS_ROWS)
      epsv = epsg[(size_t)t*EPS_ROWSZ + (size_t)b*MCAND + (size_t)lane];

    // --- G: q_c = sum_n relu(T1[r][n] + a*T2[r][n]) * W3[n] ---
    if (gact){
      const float av = AQ[gc];            // LDS broadcast (8 lanes same addr)
      int rk = 0;
#pragma unroll
      for (int i = 0; i < 13; ++i) rk += (st_r[i] < av) ? 1 : 0;
      rk += DPPI(rk, 0xB1);
      rk += DPPI(rk, 0x4E);
      rk += iswap4(rk);
      // stride-uniform addressing: byte base once, imm-offset b64 reads
      const char* rowp = (const char*)T2D + (((rk*HID) + gj) << 3);
      float acc = 0.0f;
#pragma unroll
      for (int i = 0; i < 12; ++i){
        float2 tv = *(const float2*)(rowp + (i << 6));   // n = gj + 8i
        float h = fmaxf(fmaf(av, tv.y, tv.x), 0.0f);
        acc = fmaf(h, w3r[i], acc);
      }
      if (gj < 4){                        // tail n = 96+gj (others added +0)
        float2 tv = *(const float2*)(rowp + (12 << 6));
        float h = fmaxf(fmaf(av, tv.y, tv.x), 0.0f);
        acc = fmaf(h, w3r[12], acc);
      }
      acc = DPPADD(acc, 0xB1);
      acc = DPPADD(acc, 0x4E);
      acc += fswap4(acc);
      if (gj == 0) AQ[gc] = acc;          // q overwrites a (own group's slot)
    }
    // --- fallback: per-iter eps on wave 7 (VALU only, LDS write) ---
    if (!EPSG && wv == 7 && t < EPS_ROWS && lane < MCAND){
      uint32_t gidx = (uint32_t)b*MCAND + (uint32_t)lane;
      uint32_t r0, r1, bits;
      if (gidx < 102400u){ tf2x32(kk0,kk1,gidx,gidx+102400u,r0,r1); bits = r0; }
      else               { tf2x32(kk0,kk1,gidx-102400u,gidx,r0,r1); bits = r1; }
      EPB[lane] = bits2norm(bits);
    }
    bar_lgkm();        // B1: q(t) (+fallback eps) visible; eps load in flight

    // --- S: wave0 stats (prio-boosted); (fallback) wave7 computes kk(t+1) ---
    if (wv == 0){
      __builtin_amdgcn_s_setprio(1);
      float q = (lane < MCAND) ? (AQ[lane] + sB3v) : -INFINITY;
      // sort 32-halves in opposite directions, j=32 max-merge -> top-32 multiset
      float v = q;
#define BST(KK, JJ, PV) { float pv = (PV); bool lower = (lane & (JJ)) == 0; \
        bool asc = (lane & (KK)) != 0; float mn = fminf(v, pv), mx = fmaxf(v, pv); \
        v = (lower == asc) ? mn : mx; }
      BST(2, 1,  DPPF(v, 0xB1))
      BST(4, 2,  DPPF(v, 0x4E))
      BST(4, 1,  DPPF(v, 0xB1))
      BST(8, 4,  fswap4(v))
      BST(8, 2,  DPPF(v, 0x4E))
      BST(8, 1,  DPPF(v, 0xB1))
      BST(16, 8, fswap8(v))
      BST(16, 4, fswap4(v))
      BST(16, 2, DPPF(v, 0x4E))
      BST(16, 1, DPPF(v, 0xB1))
      BST(32, 16, fswap16(v))
      BST(32, 8,  fswap8(v))
      BST(32, 4,  fswap4(v))
      BST(32, 2,  DPPF(v, 0x4E))
      BST(32, 1,  DPPF(v, 0xB1))
#undef BST
      {
        float pv = fswap32(v);
        v = ((lane & 32) == 0) ? fmaxf(v, pv) : fminf(v, pv);
      }
      // sum / sum-of-squares over lanes 0..31 (same add order as r2..r10)
      float sv = (lane < NTOP) ? v : 0.0f;
      sv += fswap32(sv);
      sv += fswap16(sv);
      sv += fswap8(sv);
      sv += fswap4(sv);
      sv = DPPADD(sv, 0x4E);
      sv = DPPADD(sv, 0xB1);
      float mun = sv / 32.0f;
      float dv = (lane < NTOP) ? (v - mun) : 0.0f;
      float s2 = dv*dv;
      s2 += fswap32(s2);
      s2 += fswap16(s2);
      s2 += fswap8(s2);
      s2 += fswap4(s2);
      s2 = DPPADD(s2, 0x4E);
      s2 = DPPADD(s2, 0xB1);
      float stdv = sqrtf(s2 / 31.0f);
      if (t == 98){
        if (lane == 0) out[b] = mun * 6.2831854820251465f;  // fp32(2*pi)
      } else if (lane < MCAND){
        float e = EPSG ? epsv : EPB[lane];   // vmcnt wait lands HERE (hidden)
        AQ[lane] = fmaf(stdv, e, mun);       // a(t+1)
      }
      __builtin_amdgcn_s_setprio(0);
    } else if (!EPSG && wv == 7 && t < EPS_ROWS){
      uint32_t nt = (uint32_t)(t + 1);
      { uint32_t i0 = 2u*nt;      uint32_t ii = (i0 < 99u) ? i0 : (i0 - 99u);
        uint32_t x,y; tf2x32(A1k,B1k, ii, 99u+ii, x, y); kk0 = (i0 < 99u) ? x : y; }
      { uint32_t i1 = 2u*nt + 1u; uint32_t ii = (i1 < 99u) ? i1 : (i1 - 99u);
        uint32_t x,y; tf2x32(A1k,B1k, ii, 99u+ii, x, y); kk1 = (i1 < 99u) ? x : y; }
    }
    bar_lgkm();        // B2: a(t+1) visible
  }
}

extern "C" void kernel_launch(void* const* d_in, const int* in_sizes, int n_in,
                              void* d_out, int out_size, void* d_ws, size_t ws_size,
                              hipStream_t stream) {
  const float* states = (const float*)d_in[0];
  const float* W1     = (const float*)d_in[1];
  const float* b1     = (const float*)d_in[2];
  const float* W2     = (const float*)d_in[3];
  const float* b2     = (const float*)d_in[4];
  const float* W3     = (const float*)d_in[5];
  const float* b3     = (const float*)d_in[6];
  float* out = (float*)d_out;

  if (d_ws != nullptr && ws_size >= WS_NEED){
    uint32_t* K = (uint32_t*)d_ws;
    float*    E = (float*)((char*)d_ws + 1024);
    hipLaunchKernelGGL(keys_kernel, dim3(1), dim3(128), 0, stream, K);
    hipLaunchKernelGGL(eps_kernel, dim3(EPS_ROWS*102400/256), dim3(256), 0, stream, K, E);
    hipLaunchKernelGGL(HIP_KERNEL_NAME(cem_kernel<true>), dim3(BATCH), dim3(512), 0, stream,
                       states, W1, b1, W2, b2, W3, b3, (const float*)E, out);
  } else {
    hipLaunchKernelGGL(HIP_KERNEL_NAME(cem_kernel<false>), dim3(BATCH), dim3(512), 0, stream,
                       states, W1, b1, W2, b2, W3, b3, (const float*)nullptr, out);
  }
}